// Round 8
// baseline (55.416 us; speedup 1.0000x reference)
//
#include <hip/hip_runtime.h>

namespace {

constexpr int H = 512;
constexpr int W = 512;
constexpr float EPSV   = 1e-6f;
constexpr float NMAXV  = 0.85f;
constexpr float LOG2E  = 1.4426950408889634f;

typedef float f4v __attribute__((ext_vector_type(4)));

__device__ __forceinline__ float fexp2(float x) {
#if __has_builtin(__builtin_amdgcn_exp2f)
    return __builtin_amdgcn_exp2f(x);
#else
    return exp2f(x);
#endif
}
__device__ __forceinline__ float flog2(float x) {
#if __has_builtin(__builtin_amdgcn_logf)
    return __builtin_amdgcn_logf(x);
#else
    return log2f(x);
#endif
}

__device__ __forceinline__ void unpack(const float4 v, float o[4]) {
    o[0] = v.x; o[1] = v.y; o[2] = v.z; o[3] = v.w;
}

// Thread shape: 2 rows x 4 px (16B/lane contiguous).
// Block shape: 8 waves = 8 consecutive row-pairs (16 rows) x half-W ->
//   u/v vertical halo overhead 12.5%; halo rows shared with the vertically
//   adjacent block via same-XCD L2 (chunked swizzle).
// Horizontal neighbors via intra-wave __shfl; only the half-row seam lane
//   does a 1-active-lane scalar load.
__global__ __launch_bounds__(512) void lef_kernel(
    const float* __restrict__ u,  const float* __restrict__ v,
    const float* __restrict__ u0, const float* __restrict__ p,
    const float* __restrict__ q,
    const float* __restrict__ s_alpha, const float* __restrict__ s_beta,
    const float* __restrict__ s_kappa, const float* __restrict__ s_lam,
    const float* __restrict__ s_omega,
    float* __restrict__ out_u, float* __restrict__ out_v)
{
    const float alpha = s_alpha[0];
    const float beta  = s_beta[0];
    const float kappa = s_kappa[0];
    const float lam   = s_lam[0];
    const float omega = s_omega[0];
    const float nk2    = (1.0f / (kappa * kappa)) * LOG2E;   // c_edge = 2^(-g*nk2)
    const float w_cand = omega * (1.0f - lam);
    const float w_u0   = omega * lam;
    const float w_self = 1.0f - omega;

    // ---- XCD-chunked bijective swizzle (grid = 3072 = 8 * 384) ----
    const int bid0 = blockIdx.x;
    const int work = (bid0 & 7) * 384 + (bid0 >> 3);

    // work -> (plane, half, vblock); consecutive work = vertical sweep.
    const int vblock = work & 31;        // 32 vblocks (16 rows each) per half-plane
    const int ph     = work >> 5;        // plane*2 + half
    const int half   = ph & 1;
    const int plane  = ph >> 1;

    const int wv   = threadIdx.x >> 6;   // wave in block: row-pair 0..7
    const int lane = threadIdx.x & 63;
    const int x0   = ((half << 6) + lane) << 2;   // contiguous 256px per wave
    const int y0   = ((vblock << 3) + wv) << 1;   // 16 rows per block
    const int y1   = y0 + 1;
    const int ym   = (y0 > 0) ? y0 - 1 : 0;
    const int y2   = (y1 < H - 1) ? y1 + 1 : H - 1;

    const int pb = plane * (H * W);
    const int rm = pb + ym * W + x0;
    const int r0 = pb + y0 * W + x0;
    const int r1 = pb + y1 * W + x0;
    const int r2 = pb + y2 * W + x0;

    // ---- coalesced float4 loads, issued up front ----
    float u_m[4], u_0[4], u_1[4], u_2[4];
    float v_m[4], v_0[4], v_1[4], v_2[4];
    float u0_0[4], u0_1[4], p_0[4], p_1[4], q_0[4], q_1[4];
    unpack(*(const float4*)(u + rm), u_m);
    unpack(*(const float4*)(u + r0), u_0);
    unpack(*(const float4*)(u + r1), u_1);
    unpack(*(const float4*)(u + r2), u_2);
    unpack(*(const float4*)(v + rm), v_m);
    unpack(*(const float4*)(v + r0), v_0);
    unpack(*(const float4*)(v + r1), v_1);
    unpack(*(const float4*)(v + r2), v_2);
    unpack(*(const float4*)(u0 + r0), u0_0);
    unpack(*(const float4*)(u0 + r1), u0_1);
    unpack(*(const float4*)(p + r0), p_0);
    unpack(*(const float4*)(p + r1), p_1);
    unpack(*(const float4*)(q + r0), q_0);
    unpack(*(const float4*)(q + r1), q_1);

    // ---- horizontal neighbors via intra-wave shuffle ----
    float ulf0 = __shfl_up(u_0[3], 1);
    float ulf1 = __shfl_up(u_1[3], 1);
    float vlf0 = __shfl_up(v_0[3], 1);
    float vlf1 = __shfl_up(v_1[3], 1);
    float urt0 = __shfl_down(u_0[0], 1);
    float urt1 = __shfl_down(u_1[0], 1);
    float vrt0 = __shfl_down(v_0[0], 1);
    float vrt1 = __shfl_down(v_1[0], 1);

    const bool left_half = (half == 0);  // wave-uniform
    if (lane == 0) {
        if (left_half) {            // true image edge -> clamp
            ulf0 = u_0[0]; ulf1 = u_1[0]; vlf0 = v_0[0]; vlf1 = v_1[0];
        } else {                    // seam at x=256: fetch x=255 (1 active lane)
            ulf0 = u[r0 - 1]; ulf1 = u[r1 - 1];
            vlf0 = v[r0 - 1]; vlf1 = v[r1 - 1];
        }
    }
    if (lane == 63) {
        if (!left_half) {           // true image edge -> clamp
            urt0 = u_0[3]; urt1 = u_1[3]; vrt0 = v_0[3]; vrt1 = v_1[3];
        } else {                    // seam at x=255: fetch x=256 (1 active lane)
            urt0 = u[r0 + 4]; urt1 = u[r1 + 4];
            vrt0 = v[r0 + 4]; vrt1 = v[r1 + 4];
        }
    }

    // ---- per-row stencil + pointwise ----
#pragma unroll
    for (int r = 0; r < 2; ++r) {
        const float* uu  = r ? u_0  : u_m;
        const float* uc  = r ? u_1  : u_0;
        const float* ud  = r ? u_2  : u_1;
        const float* vu  = r ? v_0  : v_m;
        const float* vc  = r ? v_1  : v_0;
        const float* vd  = r ? v_2  : v_1;
        const float* u0a = r ? u0_1 : u0_0;
        const float* pa  = r ? p_1  : p_0;
        const float* qa  = r ? q_1  : q_0;
        const float ulf[4] = {r ? ulf1 : ulf0, uc[0], uc[1], uc[2]};
        const float urt[4] = {uc[1], uc[2], uc[3], r ? urt1 : urt0};
        const float vlf[4] = {r ? vlf1 : vlf0, vc[0], vc[1], vc[2]};
        const float vrt[4] = {vc[1], vc[2], vc[3], r ? vrt1 : vrt0};

        f4v ou, ov;
#pragma unroll
        for (int j = 0; j < 4; ++j) {
            const float uavg = 0.25f * (uu[j] + ud[j] + ulf[j] + urt[j]);
            const float ugx  = 0.5f * (urt[j] - ulf[j]);
            const float ugy  = 0.5f * (ud[j] - uu[j]);
            const float ugsq = ugx * ugx + ugy * ugy;
            const float vavg = 0.25f * (vu[j] + vd[j] + vlf[j] + vrt[j]);
            const float vgx  = 0.5f * (vrt[j] - vlf[j]);
            const float vgy  = 0.5f * (vd[j] - vu[j]);
            const float vgsq = vgx * vgx + vgy * vgy;

            const float u_safe = fmaxf(uc[j], EPSV);
            const float v_safe = fmaxf(vc[j], EPSV);
            const float N_u = fminf(pa[j] * fexp2(alpha * flog2(v_safe)), NMAXV);
            const float N_v = fminf(qa[j] * fexp2(beta  * flog2(u_safe)), NMAXV);
            const float ce_u = fexp2(-ugsq * nk2);
            const float ce_v = fexp2(-vgsq * nk2);
            const float u_sm = uavg + N_u * 0.25f;
            const float v_sm = vavg + N_v * 0.25f;
            const float u_cand = ce_u * u_sm + (1.0f - ce_u) * uc[j];
            const float v_cand = ce_v * v_sm + (1.0f - ce_v) * vc[j];
            ou[j] = w_self * uc[j] + w_cand * u_cand + w_u0 * u0a[j];
            ov[j] = w_self * vc[j] + w_cand * v_cand + w_u0 * u0a[j];
        }
        const int rw = r ? r1 : r0;
        __builtin_nontemporal_store(ou, (f4v*)(out_u + rw));
        __builtin_nontemporal_store(ov, (f4v*)(out_v + rw));
    }
}

} // namespace

extern "C" void kernel_launch(void* const* d_in, const int* in_sizes, int n_in,
                              void* d_out, int out_size, void* d_ws, size_t ws_size,
                              hipStream_t stream)
{
    const float* u  = (const float*)d_in[0];
    const float* v  = (const float*)d_in[1];
    const float* u0 = (const float*)d_in[2];
    const float* p  = (const float*)d_in[3];
    const float* q  = (const float*)d_in[4];
    const float* s_alpha = (const float*)d_in[5];
    const float* s_beta  = (const float*)d_in[6];
    const float* s_kappa = (const float*)d_in[7];
    const float* s_lam   = (const float*)d_in[8];
    const float* s_omega = (const float*)d_in[9];

    const int n_elems = in_sizes[0];          // 16*3*512*512
    float* out_u = (float*)d_out;
    float* out_v = (float*)d_out + n_elems;

    // grid: 48 planes x 2 halves x 32 vblocks = 3072 blocks (divisible by 8)
    const int grid  = 48 * 2 * 32;
    const int block = 512;

    lef_kernel<<<grid, block, 0, stream>>>(u, v, u0, p, q,
                                           s_alpha, s_beta, s_kappa, s_lam, s_omega,
                                           out_u, out_v);
}

// Round 9
// 53.633 us; speedup vs baseline: 1.0333x; 1.0333x over previous
//
#include <hip/hip_runtime.h>

namespace {

constexpr int H = 512;
constexpr int W = 512;
constexpr float EPSV   = 1e-6f;
constexpr float NMAXV  = 0.85f;
constexpr float LOG2E  = 1.4426950408889634f;

typedef float f4v __attribute__((ext_vector_type(4)));

__device__ __forceinline__ float fexp2(float x) {
#if __has_builtin(__builtin_amdgcn_exp2f)
    return __builtin_amdgcn_exp2f(x);
#else
    return exp2f(x);
#endif
}
__device__ __forceinline__ float flog2(float x) {
#if __has_builtin(__builtin_amdgcn_logf)
    return __builtin_amdgcn_logf(x);
#else
    return log2f(x);
#endif
}

__device__ __forceinline__ void unpack(const float4 v, float o[4]) {
    o[0] = v.x; o[1] = v.y; o[2] = v.z; o[3] = v.w;
}

// Thread shape: 2 rows x 4 px (16B/lane contiguous).
// Block shape: 4 waves = 4 consecutive row-pairs (8 rows) x half-W; halo rows
//   shared with the vertically adjacent block via same-XCD L2 (chunked swizzle).
// Horizontal neighbors via intra-wave __shfl; only the half-row seam lane
//   does a 1-active-lane scalar load.
// This is the round-7 configuration: best measured (54.0 us, FETCH 124 MB).
__global__ __launch_bounds__(256) void lef_kernel(
    const float* __restrict__ u,  const float* __restrict__ v,
    const float* __restrict__ u0, const float* __restrict__ p,
    const float* __restrict__ q,
    const float* __restrict__ s_alpha, const float* __restrict__ s_beta,
    const float* __restrict__ s_kappa, const float* __restrict__ s_lam,
    const float* __restrict__ s_omega,
    float* __restrict__ out_u, float* __restrict__ out_v)
{
    const float alpha = s_alpha[0];
    const float beta  = s_beta[0];
    const float kappa = s_kappa[0];
    const float lam   = s_lam[0];
    const float omega = s_omega[0];
    const float nk2    = (1.0f / (kappa * kappa)) * LOG2E;   // c_edge = 2^(-g*nk2)
    const float w_cand = omega * (1.0f - lam);
    const float w_u0   = omega * lam;
    const float w_self = 1.0f - omega;

    // ---- XCD-chunked bijective swizzle (grid = 6144 = 8 * 768) ----
    const int bid0 = blockIdx.x;
    const int work = (bid0 & 7) * 768 + (bid0 >> 3);

    // work -> (plane, half, vblock); consecutive work = vertical sweep.
    const int vblock = work & 63;        // 64 vblocks per half-plane
    const int ph     = work >> 6;        // plane*2 + half
    const int half   = ph & 1;
    const int plane  = ph >> 1;

    const int wv   = threadIdx.x >> 6;   // wave in block: row-pair 0..3
    const int lane = threadIdx.x & 63;
    const int x0   = ((half << 6) + lane) << 2;   // contiguous 256px per wave
    const int y0   = ((vblock << 2) + wv) << 1;   // 8 rows per block
    const int y1   = y0 + 1;
    const int ym   = (y0 > 0) ? y0 - 1 : 0;
    const int y2   = (y1 < H - 1) ? y1 + 1 : H - 1;

    const int pb = plane * (H * W);
    const int rm = pb + ym * W + x0;
    const int r0 = pb + y0 * W + x0;
    const int r1 = pb + y1 * W + x0;
    const int r2 = pb + y2 * W + x0;

    // ---- coalesced float4 loads, issued up front ----
    float u_m[4], u_0[4], u_1[4], u_2[4];
    float v_m[4], v_0[4], v_1[4], v_2[4];
    float u0_0[4], u0_1[4], p_0[4], p_1[4], q_0[4], q_1[4];
    unpack(*(const float4*)(u + rm), u_m);
    unpack(*(const float4*)(u + r0), u_0);
    unpack(*(const float4*)(u + r1), u_1);
    unpack(*(const float4*)(u + r2), u_2);
    unpack(*(const float4*)(v + rm), v_m);
    unpack(*(const float4*)(v + r0), v_0);
    unpack(*(const float4*)(v + r1), v_1);
    unpack(*(const float4*)(v + r2), v_2);
    unpack(*(const float4*)(u0 + r0), u0_0);
    unpack(*(const float4*)(u0 + r1), u0_1);
    unpack(*(const float4*)(p + r0), p_0);
    unpack(*(const float4*)(p + r1), p_1);
    unpack(*(const float4*)(q + r0), q_0);
    unpack(*(const float4*)(q + r1), q_1);

    // ---- horizontal neighbors via intra-wave shuffle ----
    float ulf0 = __shfl_up(u_0[3], 1);
    float ulf1 = __shfl_up(u_1[3], 1);
    float vlf0 = __shfl_up(v_0[3], 1);
    float vlf1 = __shfl_up(v_1[3], 1);
    float urt0 = __shfl_down(u_0[0], 1);
    float urt1 = __shfl_down(u_1[0], 1);
    float vrt0 = __shfl_down(v_0[0], 1);
    float vrt1 = __shfl_down(v_1[0], 1);

    const bool left_half = (half == 0);  // wave-uniform
    if (lane == 0) {
        if (left_half) {            // true image edge -> clamp
            ulf0 = u_0[0]; ulf1 = u_1[0]; vlf0 = v_0[0]; vlf1 = v_1[0];
        } else {                    // seam at x=256: fetch x=255 (1 active lane)
            ulf0 = u[r0 - 1]; ulf1 = u[r1 - 1];
            vlf0 = v[r0 - 1]; vlf1 = v[r1 - 1];
        }
    }
    if (lane == 63) {
        if (!left_half) {           // true image edge -> clamp
            urt0 = u_0[3]; urt1 = u_1[3]; vrt0 = v_0[3]; vrt1 = v_1[3];
        } else {                    // seam at x=255: fetch x=256 (1 active lane)
            urt0 = u[r0 + 4]; urt1 = u[r1 + 4];
            vrt0 = v[r0 + 4]; vrt1 = v[r1 + 4];
        }
    }

    // ---- per-row stencil + pointwise ----
#pragma unroll
    for (int r = 0; r < 2; ++r) {
        const float* uu  = r ? u_0  : u_m;
        const float* uc  = r ? u_1  : u_0;
        const float* ud  = r ? u_2  : u_1;
        const float* vu  = r ? v_0  : v_m;
        const float* vc  = r ? v_1  : v_0;
        const float* vd  = r ? v_2  : v_1;
        const float* u0a = r ? u0_1 : u0_0;
        const float* pa  = r ? p_1  : p_0;
        const float* qa  = r ? q_1  : q_0;
        const float ulf[4] = {r ? ulf1 : ulf0, uc[0], uc[1], uc[2]};
        const float urt[4] = {uc[1], uc[2], uc[3], r ? urt1 : urt0};
        const float vlf[4] = {r ? vlf1 : vlf0, vc[0], vc[1], vc[2]};
        const float vrt[4] = {vc[1], vc[2], vc[3], r ? vrt1 : vrt0};

        f4v ou, ov;
#pragma unroll
        for (int j = 0; j < 4; ++j) {
            const float uavg = 0.25f * (uu[j] + ud[j] + ulf[j] + urt[j]);
            const float ugx  = 0.5f * (urt[j] - ulf[j]);
            const float ugy  = 0.5f * (ud[j] - uu[j]);
            const float ugsq = ugx * ugx + ugy * ugy;
            const float vavg = 0.25f * (vu[j] + vd[j] + vlf[j] + vrt[j]);
            const float vgx  = 0.5f * (vrt[j] - vlf[j]);
            const float vgy  = 0.5f * (vd[j] - vu[j]);
            const float vgsq = vgx * vgx + vgy * vgy;

            const float u_safe = fmaxf(uc[j], EPSV);
            const float v_safe = fmaxf(vc[j], EPSV);
            const float N_u = fminf(pa[j] * fexp2(alpha * flog2(v_safe)), NMAXV);
            const float N_v = fminf(qa[j] * fexp2(beta  * flog2(u_safe)), NMAXV);
            const float ce_u = fexp2(-ugsq * nk2);
            const float ce_v = fexp2(-vgsq * nk2);
            const float u_sm = uavg + N_u * 0.25f;
            const float v_sm = vavg + N_v * 0.25f;
            const float u_cand = ce_u * u_sm + (1.0f - ce_u) * uc[j];
            const float v_cand = ce_v * v_sm + (1.0f - ce_v) * vc[j];
            ou[j] = w_self * uc[j] + w_cand * u_cand + w_u0 * u0a[j];
            ov[j] = w_self * vc[j] + w_cand * v_cand + w_u0 * u0a[j];
        }
        const int rw = r ? r1 : r0;
        __builtin_nontemporal_store(ou, (f4v*)(out_u + rw));
        __builtin_nontemporal_store(ov, (f4v*)(out_v + rw));
    }
}

} // namespace

extern "C" void kernel_launch(void* const* d_in, const int* in_sizes, int n_in,
                              void* d_out, int out_size, void* d_ws, size_t ws_size,
                              hipStream_t stream)
{
    const float* u  = (const float*)d_in[0];
    const float* v  = (const float*)d_in[1];
    const float* u0 = (const float*)d_in[2];
    const float* p  = (const float*)d_in[3];
    const float* q  = (const float*)d_in[4];
    const float* s_alpha = (const float*)d_in[5];
    const float* s_beta  = (const float*)d_in[6];
    const float* s_kappa = (const float*)d_in[7];
    const float* s_lam   = (const float*)d_in[8];
    const float* s_omega = (const float*)d_in[9];

    const int n_elems = in_sizes[0];          // 16*3*512*512
    float* out_u = (float*)d_out;
    float* out_v = (float*)d_out + n_elems;

    // grid: 48 planes x 2 halves x 64 vblocks = 6144 blocks (divisible by 8)
    const int grid  = 48 * 2 * 64;
    const int block = 256;

    lef_kernel<<<grid, block, 0, stream>>>(u, v, u0, p, q,
                                           s_alpha, s_beta, s_kappa, s_lam, s_omega,
                                           out_u, out_v);
}